// Round 1
// baseline (2922.108 us; speedup 1.0000x reference)
//
#include <hip/hip_runtime.h>

// CatanGNN: 2-layer hetero GATv2 on MI355X (gfx950).
// Round 4: (a) split fused gat3 into edge-parallel score + dst-thread softmax +
// dst-wave aggregation (kills the 12-shuffle + 4-exp per-edge serial chain);
// (b) register-direct MFMA GEMM with pre-converted bf16 W^T (kills per-block
// LDS staging of 64KB fp32 W).
// N=100000/type, E=300000/relation, HID=128, HEADS=2, C=64.

#define NN 100000
#define NE 300000
#define NH (NN * 128)
#define NB 391  // ceil(NN/256)

typedef __attribute__((ext_vector_type(8))) short short8;   // 8 bf16 (4 VGPRs)
typedef __attribute__((ext_vector_type(4))) float f32x4;    // MFMA acc

__device__ __forceinline__ float bf2f(unsigned short h) {
    return __uint_as_float(((unsigned)h) << 16);
}
__device__ __forceinline__ unsigned short f2bf(float x) {  // RNE
    unsigned u = __float_as_uint(x);
    return (unsigned short)((u + 0x7FFFu + ((u >> 16) & 1u)) >> 16);
}

struct EPtrs { const int* p[9]; };
struct G6 { const unsigned short* A[6]; const unsigned short* WT[6]; unsigned short* O[6]; };
struct W4 { const float* in[4]; unsigned short* out[4]; };
struct ScoA {
    const unsigned short* PL[3];
    const unsigned short* PR[3];
    const int* csrc[3];
    const int* cdst[3];
    const float* att[3];
    float2* esc[3];
};
struct SfmA { const int* rowp[3]; float2* esc[3]; float2* denom[3]; };
struct AggA {
    const unsigned short* PL[3];
    const int* rowp[3];
    const int* csrc[3];
    const float2* alpha[3];
    const float2* denom[3];
    const float* bias[3];
};

// ---------------- input projection: h = x@W + b -> bf16 ----------------
__global__ void inproj_k(const float* __restrict__ X, const float* __restrict__ W,
                         const float* __restrict__ b, unsigned short* __restrict__ H, int M) {
    int w = (int)((blockIdx.x * blockDim.x + threadIdx.x) >> 6);
    int lane = threadIdx.x & 63;
    if (w >= M) return;
    const float* x = X + (long)w * 16;
    float a0 = 0.f, a1 = 0.f;
#pragma unroll
    for (int k = 0; k < 16; ++k) {
        float xv = x[k];
        a0 = fmaf(xv, W[k * 128 + lane], a0);
        a1 = fmaf(xv, W[k * 128 + 64 + lane], a1);
    }
    H[(long)w * 128 + lane] = f2bf(a0 + b[lane]);
    H[(long)w * 128 + 64 + lane] = f2bf(a1 + b[64 + lane]);
}

// ---------------- W -> bf16 transposed [n][k], once per call ----------------
__global__ void wcvt_k(W4 w) {
    int b = blockIdx.x;          // 0..35 : a*9 + r
    int a = b / 9, r = b % 9;
    const float* in = w.in[a] + (long)r * 16384;
    unsigned short* out = w.out[a] + (long)r * 16384;
#pragma unroll 4
    for (int it = 0; it < 64; ++it) {
        int idx = it * 256 + threadIdx.x;
        int k = idx >> 7, n = idx & 127;
        out[n * 128 + k] = f2bf(in[idx]);  // read coalesced, write strided (tiny)
    }
}

// ---------------- batched MFMA GEMM: O[g] = A[g] @ W[g], bf16 in/out ----------------
// Register-direct: B-fragments read straight from the 32KB bf16 W^T table
// (same addresses across all 4 waves -> L1 broadcast). No LDS.
__global__ __launch_bounds__(256) void gemm6_k(G6 g, int M) {
    int which = blockIdx.y;
    const unsigned short* A = g.A[which];
    const unsigned short* WT = g.WT[which];
    unsigned short* O = g.O[which];
    int tid = threadIdx.x;
    int wv = tid >> 6, lane = tid & 63;
    int quad = lane >> 4, l15 = lane & 15;
    long rowbase = (long)blockIdx.x * 64 + wv * 16;
    long arow = rowbase + l15;
    if (arow > M - 1) arow = M - 1;  // clamp (ws-backed, safe)
    f32x4 acc[8];
#pragma unroll
    for (int n = 0; n < 8; ++n) acc[n] = (f32x4){0.f, 0.f, 0.f, 0.f};
#pragma unroll
    for (int kb = 0; kb < 4; ++kb) {
        short8 a = *(const short8*)(A + arow * 128 + kb * 32 + quad * 8);
#pragma unroll
        for (int n = 0; n < 8; ++n) {
            short8 b = *(const short8*)(WT + (n * 16 + l15) * 128 + kb * 32 + quad * 8);
            acc[n] = __builtin_amdgcn_mfma_f32_16x16x32_bf16(a, b, acc[n], 0, 0, 0);
        }
    }
#pragma unroll
    for (int n = 0; n < 8; ++n)
#pragma unroll
        for (int r = 0; r < 4; ++r) {
            long row = rowbase + quad * 4 + r;
            if (row < M) O[row * 128 + n * 16 + l15] = f2bf(acc[n][r]);
        }
}

// ---------------- CSR build (once per call; reused by both layers) ----------------
__global__ void count_k(EPtrs ep, int* __restrict__ deg) {
    int r = blockIdx.y;
    int e = blockIdx.x * 256 + threadIdx.x;
    if (e >= NE) return;
    atomicAdd(&deg[r * NN + ep.p[r][NE + e]], 1);
}

__global__ void scanA_k(const int* __restrict__ deg, int* __restrict__ bsum) {
    __shared__ int sm[256];
    int r = blockIdx.y, b = blockIdx.x, t = threadIdx.x;
    int i = b * 256 + t;
    sm[t] = (i < NN) ? deg[r * NN + i] : 0;
    __syncthreads();
#pragma unroll
    for (int o = 128; o; o >>= 1) {
        if (t < o) sm[t] += sm[t + o];
        __syncthreads();
    }
    if (t == 0) bsum[r * NB + b] = sm[0];
}

__global__ void scanB_k(int* __restrict__ bsum) {
    __shared__ int sm[512];
    int r = blockIdx.x, t = threadIdx.x;
    int v = (t < NB) ? bsum[r * NB + t] : 0;
    sm[t] = v;
    __syncthreads();
    for (int o = 1; o < 512; o <<= 1) {
        int x = (t >= o) ? sm[t - o] : 0;
        __syncthreads();
        sm[t] += x;
        __syncthreads();
    }
    if (t < NB) bsum[r * NB + t] = sm[t] - v;
}

__global__ void scanC_k(int* __restrict__ deg, const int* __restrict__ bsum,
                        int* __restrict__ rowp) {
    __shared__ int sm[256];
    int r = blockIdx.y, b = blockIdx.x, t = threadIdx.x;
    int i = b * 256 + t;
    int v = (i < NN) ? deg[r * NN + i] : 0;
    sm[t] = v;
    __syncthreads();
    for (int o = 1; o < 256; o <<= 1) {
        int x = (t >= o) ? sm[t - o] : 0;
        __syncthreads();
        sm[t] += x;
        __syncthreads();
    }
    int excl = sm[t] - v + bsum[r * NB + b];
    if (i < NN) {
        rowp[r * (NN + 1) + i] = excl;
        deg[r * NN + i] = excl;  // becomes scatter cursor
        if (i == NN - 1) rowp[r * (NN + 1) + NN] = excl + v;
    }
}

__global__ void scat_k(EPtrs ep, int* __restrict__ cursor, int* __restrict__ csrc,
                       int* __restrict__ cdst) {
    int r = blockIdx.y;
    int e = blockIdx.x * 256 + threadIdx.x;
    if (e >= NE) return;
    int s = ep.p[r][e], d = ep.p[r][NE + e];
    int pos = atomicAdd(&cursor[r * NN + d], 1);
    csrc[(long)r * NE + pos] = s;
    cdst[(long)r * NE + pos] = d;
}

// ---------- phase 1: edge-parallel attention scores (one lane per edge) ----------
__global__ void score_k(ScoA g) {
    int j = blockIdx.y;
    int i = blockIdx.x * 256 + threadIdx.x;
    if (i >= NE) return;
    int s = g.csrc[j][i], d = g.cdst[j][i];
    const unsigned short* pls = g.PL[j] + (long)s * 128;
    const unsigned short* prd = g.PR[j] + (long)d * 128;
    const float* att = g.att[j];
    float e0a = 0.f, e0b = 0.f, e1a = 0.f, e1b = 0.f;
#pragma unroll
    for (int kb = 0; kb < 16; ++kb) {  // 8 channels per chunk; kb<8 head0, else head1
        short8 a = *(const short8*)(pls + kb * 8);
        short8 b = *(const short8*)(prd + kb * 8);
#pragma unroll
        for (int u = 0; u < 8; ++u) {
            float x = bf2f((unsigned short)a[u]) + bf2f((unsigned short)b[u]);
            float lv = fmaxf(x, 0.f) + 0.2f * fminf(x, 0.f);  // leaky_relu(x, 0.2)
            float av = att[kb * 8 + u];                        // wave-uniform
            if (kb < 8) {
                if (u & 1) e0b = fmaf(lv, av, e0b); else e0a = fmaf(lv, av, e0a);
            } else {
                if (u & 1) e1b = fmaf(lv, av, e1b); else e1a = fmaf(lv, av, e1a);
            }
        }
    }
    g.esc[j][i] = make_float2(e0a + e0b, e1a + e1b);
}

// ---------- phase 2: per-dst softmax (one THREAD per dst; scores L2-hot) ----------
// Writes unnormalized p = exp(e - max) in place, denom per dst per head.
__global__ void sfm_k(SfmA g) {
    int j = blockIdx.y;
    int t = blockIdx.x * 256 + threadIdx.x;
    if (t >= NN) return;
    int beg = g.rowp[j][t], end = g.rowp[j][t + 1];
    float2* e = g.esc[j];
    float m0 = -1e30f, m1 = -1e30f;
    for (int i = beg; i < end; ++i) {
        float2 v = e[i];
        m0 = fmaxf(m0, v.x);
        m1 = fmaxf(m1, v.y);
    }
    float s0 = 0.f, s1 = 0.f;
    for (int i = beg; i < end; ++i) {
        float2 v = e[i];
        float p0 = __expf(v.x - m0), p1 = __expf(v.y - m1);
        s0 += p0;
        s1 += p1;
        e[i] = make_float2(p0, p1);
    }
    g.denom[j][t] = make_float2(s0, s1);
}

// ---------- phase 3: aggregation (one wave per dst; lane = channels 2l,2l+1) ----------
// Inner loop: 1 uniform p load + 1 uniform src load + 1 dword gather + 2 FMA.
__global__ void agg_k(AggA g, float* __restrict__ outF, unsigned short* __restrict__ outH,
                      int mode) {  // mode 0: relu -> bf16 outH ; mode 1: fp32 outF
    int w = (int)((blockIdx.x * blockDim.x + threadIdx.x) >> 6);
    int l = threadIdx.x & 63;  // head h = l>>5
    if (w >= NN) return;
    float accx = 0.f, accy = 0.f;
#pragma unroll
    for (int j = 0; j < 3; ++j) {
        const unsigned short* PL = g.PL[j];
        const int* cs = g.csrc[j];
        const float2* al = g.alpha[j];
        int beg = g.rowp[j][w], end = g.rowp[j][w + 1];
        float ax = 0.f, ay = 0.f;
        for (int i = beg; i < end; ++i) {
            int s = cs[i];        // wave-uniform
            float2 p = al[i];     // wave-uniform
            float pv = (l < 32) ? p.x : p.y;
            unsigned gg = *(const unsigned*)(PL + (long)s * 128 + 2 * l);
            ax = fmaf(pv, bf2f((unsigned short)(gg & 0xffffu)), ax);
            ay = fmaf(pv, bf2f((unsigned short)(gg >> 16)), ay);
        }
        float2 dn = g.denom[j][w];
        float inv = 1.f / (((l < 32) ? dn.x : dn.y) + 1e-16f);
        accx += ax * inv + g.bias[j][2 * l];
        accy += ay * inv + g.bias[j][2 * l + 1];
    }
    if (mode == 0) {
        unsigned px = (unsigned)f2bf(fmaxf(accx, 0.f)) |
                      ((unsigned)f2bf(fmaxf(accy, 0.f)) << 16);
        *(unsigned*)(outH + (long)w * 128 + 2 * l) = px;   // coalesced 256B/row
    } else {
        *(float2*)(outF + (long)w * 128 + 2 * l) = make_float2(accx, accy);
    }
}

__global__ void sentinel_k(float* out) { out[0] = 123456.0f; }

extern "C" void kernel_launch(void* const* d_in, const int* in_sizes, int n_in,
                              void* d_out, int out_size, void* d_ws, size_t ws_size,
                              hipStream_t stream) {
    const float* xin[3] = {(const float*)d_in[0], (const float*)d_in[1], (const float*)d_in[2]};
    EPtrs ep;
    for (int r = 0; r < 9; ++r) ep.p[r] = (const int*)d_in[3 + r];
    const float* Win[3] = {(const float*)d_in[12], (const float*)d_in[14], (const float*)d_in[16]};
    const float* bin[3] = {(const float*)d_in[13], (const float*)d_in[15], (const float*)d_in[17]};
    const float* Wl[2] = {(const float*)d_in[18], (const float*)d_in[22]};
    const float* Wr[2] = {(const float*)d_in[19], (const float*)d_in[23]};
    const float* att[2] = {(const float*)d_in[20], (const float*)d_in[24]};
    const float* bc[2] = {(const float*)d_in[21], (const float*)d_in[25]};

    // ws layout:
    //  h1[3] h2[3] pl[3] pr[3] (bf16, NH each) | wT 4*9*16384 bf16 |
    //  esc 3*NE float2 | denom 3*NN float2 |
    //  deg 9NN | bsum 9NB | rowp 9(NN+1) | csrc 9NE | cdst 9NE (int)
    size_t nInt = (size_t)9 * NN + (size_t)9 * NB + (size_t)9 * (NN + 1) + (size_t)18 * NE;
    size_t nF = (size_t)3 * NE * 2 + (size_t)3 * NN * 2;
    size_t need = ((size_t)12 * NH + 589824) * 2 + nF * 4 + nInt * 4;
    if (ws_size < need) {
        hipMemsetAsync(d_out, 0, (size_t)out_size * 4, stream);
        sentinel_k<<<1, 1, 0, stream>>>((float*)d_out);
        return;
    }
    unsigned short* h1 = (unsigned short*)d_ws;
    unsigned short* h2 = h1 + (size_t)3 * NH;
    unsigned short* pl = h2 + (size_t)3 * NH;
    unsigned short* pr = pl + (size_t)3 * NH;
    unsigned short* wT = pr + (size_t)3 * NH;           // 4*9*16384 bf16
    float2* esc = (float2*)(wT + 589824);               // 3*NE
    float2* denomp = esc + (size_t)3 * NE;              // 3*NN
    int* deg = (int*)(denomp + (size_t)3 * NN);
    int* bsum = deg + (size_t)9 * NN;
    int* rowp = bsum + (size_t)9 * NB;
    int* csrc = rowp + (size_t)9 * (NN + 1);
    int* cdst = csrc + (size_t)9 * NE;

    static const int ST[9] = {0, 0, 1, 0, 2, 1, 2, 1, 2};
    static const int RT[3][3] = {{0, 2, 4}, {1, 6, 7}, {3, 5, 8}};  // relations per dst type

    for (int T = 0; T < 3; ++T)
        inproj_k<<<NN / 4, 256, 0, stream>>>(xin[T], Win[T], bin[T], h1 + (size_t)T * NH, NN);

    {   // pre-convert all 36 weight matrices to bf16 W^T [n][k]
        W4 w4;
        w4.in[0] = Wl[0]; w4.in[1] = Wr[0]; w4.in[2] = Wl[1]; w4.in[3] = Wr[1];
        for (int a = 0; a < 4; ++a) w4.out[a] = wT + (size_t)a * 9 * 16384;
        wcvt_k<<<36, 256, 0, stream>>>(w4);
    }

    hipMemsetAsync(deg, 0, (size_t)9 * NN * 4, stream);
    dim3 eg((NE + 255) / 256, 9), ng(NB, 9);
    count_k<<<eg, 256, 0, stream>>>(ep, deg);
    scanA_k<<<ng, 256, 0, stream>>>(deg, bsum);
    scanB_k<<<9, 512, 0, stream>>>(bsum);
    scanC_k<<<ng, 256, 0, stream>>>(deg, bsum, rowp);
    scat_k<<<eg, 256, 0, stream>>>(ep, deg, csrc, cdst);

    dim3 gg((NN + 63) / 64, 6);
    dim3 sg((NE + 255) / 256, 3), fg((NN + 255) / 256, 3);
    for (int l = 0; l < 2; ++l) {
        unsigned short* hc = (l == 0) ? h1 : h2;
        for (int T = 0; T < 3; ++T) {
            G6 g6; ScoA sc; SfmA sf; AggA ag;
            for (int j = 0; j < 3; ++j) {
                int r = RT[T][j];
                g6.A[j] = hc + (size_t)ST[r] * NH;                      // PL_j = h[src] @ Wl[r]
                g6.WT[j] = wT + (size_t)(l * 2 + 0) * 9 * 16384 + (size_t)r * 16384;
                g6.O[j] = pl + (size_t)j * NH;
                g6.A[3 + j] = hc + (size_t)T * NH;                      // PR_j = h[T] @ Wr[r]
                g6.WT[3 + j] = wT + (size_t)(l * 2 + 1) * 9 * 16384 + (size_t)r * 16384;
                g6.O[3 + j] = pr + (size_t)j * NH;
                sc.PL[j] = pl + (size_t)j * NH;
                sc.PR[j] = pr + (size_t)j * NH;
                sc.csrc[j] = csrc + (size_t)r * NE;
                sc.cdst[j] = cdst + (size_t)r * NE;
                sc.att[j] = att[l] + (size_t)r * 128;
                sc.esc[j] = esc + (size_t)j * NE;
                sf.rowp[j] = rowp + (size_t)r * (NN + 1);
                sf.esc[j] = esc + (size_t)j * NE;
                sf.denom[j] = denomp + (size_t)j * NN;
                ag.PL[j] = pl + (size_t)j * NH;
                ag.rowp[j] = rowp + (size_t)r * (NN + 1);
                ag.csrc[j] = csrc + (size_t)r * NE;
                ag.alpha[j] = esc + (size_t)j * NE;
                ag.denom[j] = denomp + (size_t)j * NN;
                ag.bias[j] = bc[l] + (size_t)r * 128;
            }
            gemm6_k<<<gg, 256, 0, stream>>>(g6, NN);
            score_k<<<sg, 256, 0, stream>>>(sc);
            sfm_k<<<fg, 256, 0, stream>>>(sf);
            if (l == 0)
                agg_k<<<NN / 4, 256, 0, stream>>>(ag, nullptr, h2 + (size_t)T * NH, 0);
            else
                agg_k<<<NN / 4, 256, 0, stream>>>(ag, (float*)d_out + (size_t)T * NH, nullptr, 1);
        }
    }
}

// Round 3
// 1942.430 us; speedup vs baseline: 1.5044x; 1.5044x over previous
//
#include <hip/hip_runtime.h>

// CatanGNN: 2-layer hetero GATv2 on MI355X (gfx950).
// Round 6 (= round 5 resubmit, portable exp2 builtin).
// Fused per-dst flash-GAT, issue-optimized:
//  - lane l -> head l>>5, channels 2(l&31),2(l&31)+1: both heads share ONE
//    5-step width-32 shuffle reduce (was 2x 6-step width-64), one online
//    softmax chain (2 exp vs 4), one dword gather per edge (was 2 ushort).
//  - att pre-scaled by log2(e) -> native v_exp_f32 via __builtin_exp2f.
//  - readfirstlane on src index -> SALU address math for the row gather.
// N=100000/type, E=300000/relation, HID=128, HEADS=2, C=64.

#define NN 100000
#define NE 300000
#define NH (NN * 128)
#define NB 391  // ceil(NN/256)
#define LOG2E 1.4426950408889634f

typedef __attribute__((ext_vector_type(8))) short short8;   // 8 bf16 (4 VGPRs)
typedef __attribute__((ext_vector_type(4))) float f32x4;    // MFMA acc

__device__ __forceinline__ float bf2f(unsigned short h) {
    return __uint_as_float(((unsigned)h) << 16);
}
__device__ __forceinline__ unsigned short f2bf(float x) {  // RNE
    unsigned u = __float_as_uint(x);
    return (unsigned short)((u + 0x7FFFu + ((u >> 16) & 1u)) >> 16);
}

struct EPtrs { const int* p[9]; };
struct G6 { const unsigned short* A[6]; const float* W[6]; unsigned short* O[6]; };
struct GatA {
    const unsigned short* PL[3];
    const unsigned short* PR[3];
    const int* rowp[3];
    const int* csrc[3];
    const float* att[3];
    const float* bias[3];
};

// ---------------- input projection: h = x@W + b -> bf16 ----------------
__global__ void inproj_k(const float* __restrict__ X, const float* __restrict__ W,
                         const float* __restrict__ b, unsigned short* __restrict__ H, int M) {
    int w = (int)((blockIdx.x * blockDim.x + threadIdx.x) >> 6);
    int lane = threadIdx.x & 63;
    if (w >= M) return;
    const float* x = X + (long)w * 16;
    float a0 = 0.f, a1 = 0.f;
#pragma unroll
    for (int k = 0; k < 16; ++k) {
        float xv = x[k];
        a0 = fmaf(xv, W[k * 128 + lane], a0);
        a1 = fmaf(xv, W[k * 128 + 64 + lane], a1);
    }
    H[(long)w * 128 + lane] = f2bf(a0 + b[lane]);
    H[(long)w * 128 + 64 + lane] = f2bf(a1 + b[64 + lane]);
}

// ---------------- batched MFMA GEMM: O[g] = A[g] @ W[g], bf16 in/out ----------------
// grid.x tiles 64 rows, grid.y = which of 6 GEMMs. Block 256 = 4 waves; wave w:
// rows w*16..+15, all 128 cols (8 n-tiles), K=128 in 4 steps of 32.
__global__ __launch_bounds__(256) void gemm6_k(G6 g, int M) {
    __shared__ unsigned short Bt[128 * 136];  // W transposed [n][k], +8 pad (2-way only)
    int which = blockIdx.y;
    const unsigned short* A = g.A[which];
    const float* W = g.W[which];
    unsigned short* O = g.O[which];
    int tid = threadIdx.x;
#pragma unroll
    for (int i = 0; i < 64; ++i) {
        int idx = i * 256 + tid;
        int k = idx >> 7, c = idx & 127;
        Bt[c * 136 + k] = f2bf(W[idx]);
    }
    __syncthreads();
    int wv = tid >> 6, lane = tid & 63;
    int quad = lane >> 4, l15 = lane & 15;
    long rowbase = (long)blockIdx.x * 64 + wv * 16;
    long arow = rowbase + l15;
    if (arow > M - 1) arow = M - 1;  // clamp (ws-backed, safe)
    f32x4 acc[8];
#pragma unroll
    for (int n = 0; n < 8; ++n) acc[n] = (f32x4){0.f, 0.f, 0.f, 0.f};
#pragma unroll
    for (int kb = 0; kb < 4; ++kb) {
        short8 a = *(const short8*)(A + arow * 128 + kb * 32 + quad * 8);
#pragma unroll
        for (int n = 0; n < 8; ++n) {
            short8 b = *(const short8*)(&Bt[(n * 16 + l15) * 136 + kb * 32 + quad * 8]);
            acc[n] = __builtin_amdgcn_mfma_f32_16x16x32_bf16(a, b, acc[n], 0, 0, 0);
        }
    }
#pragma unroll
    for (int n = 0; n < 8; ++n)
#pragma unroll
        for (int r = 0; r < 4; ++r) {
            long row = rowbase + quad * 4 + r;
            if (row < M) O[row * 128 + n * 16 + l15] = f2bf(acc[n][r]);
        }
}

// ---------------- CSR build (once per call; reused by both layers) ----------------
__global__ void count_k(EPtrs ep, int* __restrict__ deg) {
    int r = blockIdx.y;
    int e = blockIdx.x * 256 + threadIdx.x;
    if (e >= NE) return;
    atomicAdd(&deg[r * NN + ep.p[r][NE + e]], 1);
}

__global__ void scanA_k(const int* __restrict__ deg, int* __restrict__ bsum) {
    __shared__ int sm[256];
    int r = blockIdx.y, b = blockIdx.x, t = threadIdx.x;
    int i = b * 256 + t;
    sm[t] = (i < NN) ? deg[r * NN + i] : 0;
    __syncthreads();
#pragma unroll
    for (int o = 128; o; o >>= 1) {
        if (t < o) sm[t] += sm[t + o];
        __syncthreads();
    }
    if (t == 0) bsum[r * NB + b] = sm[0];
}

__global__ void scanB_k(int* __restrict__ bsum) {
    __shared__ int sm[512];
    int r = blockIdx.x, t = threadIdx.x;
    int v = (t < NB) ? bsum[r * NB + t] : 0;
    sm[t] = v;
    __syncthreads();
    for (int o = 1; o < 512; o <<= 1) {
        int x = (t >= o) ? sm[t - o] : 0;
        __syncthreads();
        sm[t] += x;
        __syncthreads();
    }
    if (t < NB) bsum[r * NB + t] = sm[t] - v;
}

__global__ void scanC_k(int* __restrict__ deg, const int* __restrict__ bsum,
                        int* __restrict__ rowp) {
    __shared__ int sm[256];
    int r = blockIdx.y, b = blockIdx.x, t = threadIdx.x;
    int i = b * 256 + t;
    int v = (i < NN) ? deg[r * NN + i] : 0;
    sm[t] = v;
    __syncthreads();
    for (int o = 1; o < 256; o <<= 1) {
        int x = (t >= o) ? sm[t - o] : 0;
        __syncthreads();
        sm[t] += x;
        __syncthreads();
    }
    int excl = sm[t] - v + bsum[r * NB + b];
    if (i < NN) {
        rowp[r * (NN + 1) + i] = excl;
        deg[r * NN + i] = excl;  // becomes scatter cursor
        if (i == NN - 1) rowp[r * (NN + 1) + NN] = excl + v;
    }
}

__global__ void scat_k(EPtrs ep, int* __restrict__ cursor, int* __restrict__ csrc) {
    int r = blockIdx.y;
    int e = blockIdx.x * 256 + threadIdx.x;
    if (e >= NE) return;
    int s = ep.p[r][e], d = ep.p[r][NE + e];
    int pos = atomicAdd(&cursor[r * NN + d], 1);
    csrc[(long)r * NE + pos] = s;
}

// ---------- fused 3-relation GATv2 per dst node (online softmax, bias, relu) ----------
// One wave per dst. Lane l: head h=l>>5, channels col=h*64+2*(l&31), col+1.
// Both heads reduce in ONE 5-step width-32 shuffle tree; one online-softmax
// chain per lane; one dword gather per edge per lane; native exp2.
__global__ void gat3_k(GatA g, float* __restrict__ outF, unsigned short* __restrict__ outH,
                       int mode) {  // mode 0: relu -> bf16 outH ; mode 1: fp32 outF
    int w = (int)((blockIdx.x * blockDim.x + threadIdx.x) >> 6);
    int l = threadIdx.x & 63;
    if (w >= NN) return;
    int col = ((l >> 5) << 6) + ((l & 31) << 1);  // h*64 + 2*(l&31)
    float acc0 = 0.f, acc1 = 0.f;
#pragma unroll
    for (int j = 0; j < 3; ++j) {
        const unsigned short* PL = g.PL[j];
        unsigned grp = *(const unsigned*)(g.PR[j] + (long)w * 128 + col);
        float gr0 = __uint_as_float(grp << 16);
        float gr1 = __uint_as_float(grp & 0xffff0000u);
        float at0 = g.att[j][col] * LOG2E;       // fold log2(e): exp(x)=exp2(x')
        float at1 = g.att[j][col + 1] * LOG2E;
        int beg = g.rowp[j][w], end = g.rowp[j][w + 1];
        float m = -1e30f, sden = 0.f, a0 = 0.f, a1 = 0.f;
        for (int i = beg; i < end; ++i) {
            int s = __builtin_amdgcn_readfirstlane(g.csrc[j][i]);  // wave-uniform -> SALU addr
            unsigned gg = *(const unsigned*)(PL + (long)s * 128 + col);
            float gl0 = __uint_as_float(gg << 16);
            float gl1 = __uint_as_float(gg & 0xffff0000u);
            float x0 = gl0 + gr0, x1 = gl1 + gr1;
            float t0 = fmaxf(x0, 0.f) + 0.2f * fminf(x0, 0.f);  // leaky_relu
            float t1 = fmaxf(x1, 0.f) + 0.2f * fminf(x1, 0.f);
            float v = t0 * at0 + t1 * at1;
            v += __shfl_xor(v, 16);  // width-32 tree: both heads reduce at once
            v += __shfl_xor(v, 8);
            v += __shfl_xor(v, 4);
            v += __shfl_xor(v, 2);
            v += __shfl_xor(v, 1);
            float mn = fmaxf(m, v);
            float sc = __builtin_exp2f(m - mn);   // v_exp_f32
            float p = __builtin_exp2f(v - mn);    // v_exp_f32
            sden = sden * sc + p;
            a0 = a0 * sc + p * gl0;
            a1 = a1 * sc + p * gl1;
            m = mn;
        }
        float inv = 1.f / (sden + 1e-16f);
        acc0 += a0 * inv + g.bias[j][col];
        acc1 += a1 * inv + g.bias[j][col + 1];
    }
    long o = (long)w * 128 + col;
    if (mode == 0) {
        unsigned px = (unsigned)f2bf(fmaxf(acc0, 0.f)) |
                      ((unsigned)f2bf(fmaxf(acc1, 0.f)) << 16);
        *(unsigned*)(outH + o) = px;  // coalesced 256B/row
    } else {
        *(float2*)(outF + o) = make_float2(acc0, acc1);
    }
}

__global__ void sentinel_k(float* out) { out[0] = 123456.0f; }

extern "C" void kernel_launch(void* const* d_in, const int* in_sizes, int n_in,
                              void* d_out, int out_size, void* d_ws, size_t ws_size,
                              hipStream_t stream) {
    const float* xin[3] = {(const float*)d_in[0], (const float*)d_in[1], (const float*)d_in[2]};
    EPtrs ep;
    for (int r = 0; r < 9; ++r) ep.p[r] = (const int*)d_in[3 + r];
    const float* Win[3] = {(const float*)d_in[12], (const float*)d_in[14], (const float*)d_in[16]};
    const float* bin[3] = {(const float*)d_in[13], (const float*)d_in[15], (const float*)d_in[17]};
    const float* Wl[2] = {(const float*)d_in[18], (const float*)d_in[22]};
    const float* Wr[2] = {(const float*)d_in[19], (const float*)d_in[23]};
    const float* att[2] = {(const float*)d_in[20], (const float*)d_in[24]};
    const float* bc[2] = {(const float*)d_in[21], (const float*)d_in[25]};

    // ws: h1[3] h2[3] pl[3] pr[3] (bf16, NH each) | deg 9NN | bsum 9NB | rowp 9(NN+1) | csrc 9NE
    size_t nInt = (size_t)9 * NN + (size_t)9 * NB + (size_t)9 * (NN + 1) + (size_t)9 * NE;
    size_t need = (size_t)12 * NH * 2 + nInt * 4;
    if (ws_size < need) {
        hipMemsetAsync(d_out, 0, (size_t)out_size * 4, stream);
        sentinel_k<<<1, 1, 0, stream>>>((float*)d_out);
        return;
    }
    unsigned short* h1 = (unsigned short*)d_ws;
    unsigned short* h2 = h1 + (size_t)3 * NH;
    unsigned short* pl = h2 + (size_t)3 * NH;
    unsigned short* pr = pl + (size_t)3 * NH;
    int* deg = (int*)(pr + (size_t)3 * NH);
    int* bsum = deg + (size_t)9 * NN;
    int* rowp = bsum + (size_t)9 * NB;
    int* csrc = rowp + (size_t)9 * (NN + 1);

    static const int ST[9] = {0, 0, 1, 0, 2, 1, 2, 1, 2};
    static const int RT[3][3] = {{0, 2, 4}, {1, 6, 7}, {3, 5, 8}};  // relations per dst type

    for (int T = 0; T < 3; ++T)
        inproj_k<<<NN / 4, 256, 0, stream>>>(xin[T], Win[T], bin[T], h1 + (size_t)T * NH, NN);

    hipMemsetAsync(deg, 0, (size_t)9 * NN * 4, stream);
    dim3 eg((NE + 255) / 256, 9), ng(NB, 9);
    count_k<<<eg, 256, 0, stream>>>(ep, deg);
    scanA_k<<<ng, 256, 0, stream>>>(deg, bsum);
    scanB_k<<<9, 512, 0, stream>>>(bsum);
    scanC_k<<<ng, 256, 0, stream>>>(deg, bsum, rowp);
    scat_k<<<eg, 256, 0, stream>>>(ep, deg, csrc);

    dim3 gg((NN + 63) / 64, 6);
    for (int l = 0; l < 2; ++l) {
        unsigned short* hc = (l == 0) ? h1 : h2;
        for (int T = 0; T < 3; ++T) {
            G6 g6;
            GatA ga;
            for (int j = 0; j < 3; ++j) {
                int r = RT[T][j];
                g6.A[j] = hc + (size_t)ST[r] * NH;               // PL_j = h[src] @ Wl[r]
                g6.W[j] = Wl[l] + (size_t)r * 16384;
                g6.O[j] = pl + (size_t)j * NH;
                g6.A[3 + j] = hc + (size_t)T * NH;               // PR_j = h[T] @ Wr[r]
                g6.W[3 + j] = Wr[l] + (size_t)r * 16384;
                g6.O[3 + j] = pr + (size_t)j * NH;
                ga.PL[j] = pl + (size_t)j * NH;
                ga.PR[j] = pr + (size_t)j * NH;
                ga.rowp[j] = rowp + (size_t)r * (NN + 1);
                ga.csrc[j] = csrc + (size_t)r * NE;
                ga.att[j] = att[l] + (size_t)r * 128;
                ga.bias[j] = bc[l] + (size_t)r * 128;
            }
            gemm6_k<<<gg, 256, 0, stream>>>(g6, NN);
            if (l == 0)
                gat3_k<<<NN / 4, 256, 0, stream>>>(ga, nullptr, h2 + (size_t)T * NH, 0);
            else
                gat3_k<<<NN / 4, 256, 0, stream>>>(ga, (float*)d_out + (size_t)T * NH, nullptr, 1);
        }
    }
}

// Round 4
// 1832.862 us; speedup vs baseline: 1.5943x; 1.0598x over previous
//
#include <hip/hip_runtime.h>

// CatanGNN: 2-layer hetero GATv2 on MI355X (gfx950).
// Round 7: gat3 is memory-LATENCY-bound (~1 outstanding gather/wave, serial
// csrc->readfirstlane->gather chain, 3 relation loops run back-to-back with
// degree~3 each). Fix: interleave the 3 relations' edge loops (independent
// online-softmax state each) + 1-deep gather prefetch per relation => ~3
// gathers in flight, trip count max(d) not sum(d). Traffic unchanged.
// N=100000/type, E=300000/relation, HID=128, HEADS=2, C=64.

#define NN 100000
#define NE 300000
#define NH (NN * 128)
#define NB 391  // ceil(NN/256)
#define LOG2E 1.4426950408889634f

typedef __attribute__((ext_vector_type(8))) short short8;   // 8 bf16 (4 VGPRs)
typedef __attribute__((ext_vector_type(4))) float f32x4;    // MFMA acc

__device__ __forceinline__ float bf2f(unsigned short h) {
    return __uint_as_float(((unsigned)h) << 16);
}
__device__ __forceinline__ unsigned short f2bf(float x) {  // RNE
    unsigned u = __float_as_uint(x);
    return (unsigned short)((u + 0x7FFFu + ((u >> 16) & 1u)) >> 16);
}

struct EPtrs { const int* p[9]; };
struct G6 { const unsigned short* A[6]; const float* W[6]; unsigned short* O[6]; };
struct GatA {
    const unsigned short* PL[3];
    const unsigned short* PR[3];
    const int* rowp[3];
    const int* csrc[3];
    const float* att[3];
    const float* bias[3];
};

// ---------------- input projection: h = x@W + b -> bf16 ----------------
__global__ void inproj_k(const float* __restrict__ X, const float* __restrict__ W,
                         const float* __restrict__ b, unsigned short* __restrict__ H, int M) {
    int w = (int)((blockIdx.x * blockDim.x + threadIdx.x) >> 6);
    int lane = threadIdx.x & 63;
    if (w >= M) return;
    const float* x = X + (long)w * 16;
    float a0 = 0.f, a1 = 0.f;
#pragma unroll
    for (int k = 0; k < 16; ++k) {
        float xv = x[k];
        a0 = fmaf(xv, W[k * 128 + lane], a0);
        a1 = fmaf(xv, W[k * 128 + 64 + lane], a1);
    }
    H[(long)w * 128 + lane] = f2bf(a0 + b[lane]);
    H[(long)w * 128 + 64 + lane] = f2bf(a1 + b[64 + lane]);
}

// ---------------- batched MFMA GEMM: O[g] = A[g] @ W[g], bf16 in/out ----------------
__global__ __launch_bounds__(256) void gemm6_k(G6 g, int M) {
    __shared__ unsigned short Bt[128 * 136];  // W transposed [n][k], +8 pad (2-way only)
    int which = blockIdx.y;
    const unsigned short* A = g.A[which];
    const float* W = g.W[which];
    unsigned short* O = g.O[which];
    int tid = threadIdx.x;
#pragma unroll
    for (int i = 0; i < 64; ++i) {
        int idx = i * 256 + tid;
        int k = idx >> 7, c = idx & 127;
        Bt[c * 136 + k] = f2bf(W[idx]);
    }
    __syncthreads();
    int wv = tid >> 6, lane = tid & 63;
    int quad = lane >> 4, l15 = lane & 15;
    long rowbase = (long)blockIdx.x * 64 + wv * 16;
    long arow = rowbase + l15;
    if (arow > M - 1) arow = M - 1;  // clamp (ws-backed, safe)
    f32x4 acc[8];
#pragma unroll
    for (int n = 0; n < 8; ++n) acc[n] = (f32x4){0.f, 0.f, 0.f, 0.f};
#pragma unroll
    for (int kb = 0; kb < 4; ++kb) {
        short8 a = *(const short8*)(A + arow * 128 + kb * 32 + quad * 8);
#pragma unroll
        for (int n = 0; n < 8; ++n) {
            short8 b = *(const short8*)(&Bt[(n * 16 + l15) * 136 + kb * 32 + quad * 8]);
            acc[n] = __builtin_amdgcn_mfma_f32_16x16x32_bf16(a, b, acc[n], 0, 0, 0);
        }
    }
#pragma unroll
    for (int n = 0; n < 8; ++n)
#pragma unroll
        for (int r = 0; r < 4; ++r) {
            long row = rowbase + quad * 4 + r;
            if (row < M) O[row * 128 + n * 16 + l15] = f2bf(acc[n][r]);
        }
}

// ---------------- CSR build (once per call; reused by both layers) ----------------
__global__ void count_k(EPtrs ep, int* __restrict__ deg) {
    int r = blockIdx.y;
    int e = blockIdx.x * 256 + threadIdx.x;
    if (e >= NE) return;
    atomicAdd(&deg[r * NN + ep.p[r][NE + e]], 1);
}

__global__ void scanA_k(const int* __restrict__ deg, int* __restrict__ bsum) {
    __shared__ int sm[256];
    int r = blockIdx.y, b = blockIdx.x, t = threadIdx.x;
    int i = b * 256 + t;
    sm[t] = (i < NN) ? deg[r * NN + i] : 0;
    __syncthreads();
#pragma unroll
    for (int o = 128; o; o >>= 1) {
        if (t < o) sm[t] += sm[t + o];
        __syncthreads();
    }
    if (t == 0) bsum[r * NB + b] = sm[0];
}

__global__ void scanB_k(int* __restrict__ bsum) {
    __shared__ int sm[512];
    int r = blockIdx.x, t = threadIdx.x;
    int v = (t < NB) ? bsum[r * NB + t] : 0;
    sm[t] = v;
    __syncthreads();
    for (int o = 1; o < 512; o <<= 1) {
        int x = (t >= o) ? sm[t - o] : 0;
        __syncthreads();
        sm[t] += x;
        __syncthreads();
    }
    if (t < NB) bsum[r * NB + t] = sm[t] - v;
}

__global__ void scanC_k(int* __restrict__ deg, const int* __restrict__ bsum,
                        int* __restrict__ rowp) {
    __shared__ int sm[256];
    int r = blockIdx.y, b = blockIdx.x, t = threadIdx.x;
    int i = b * 256 + t;
    int v = (i < NN) ? deg[r * NN + i] : 0;
    sm[t] = v;
    __syncthreads();
    for (int o = 1; o < 256; o <<= 1) {
        int x = (t >= o) ? sm[t - o] : 0;
        __syncthreads();
        sm[t] += x;
        __syncthreads();
    }
    int excl = sm[t] - v + bsum[r * NB + b];
    if (i < NN) {
        rowp[r * (NN + 1) + i] = excl;
        deg[r * NN + i] = excl;  // becomes scatter cursor
        if (i == NN - 1) rowp[r * (NN + 1) + NN] = excl + v;
    }
}

__global__ void scat_k(EPtrs ep, int* __restrict__ cursor, int* __restrict__ csrc) {
    int r = blockIdx.y;
    int e = blockIdx.x * 256 + threadIdx.x;
    if (e >= NE) return;
    int s = ep.p[r][e], d = ep.p[r][NE + e];
    int pos = atomicAdd(&cursor[r * NN + d], 1);
    csrc[(long)r * NE + pos] = s;
}

// ---------- fused 3-relation GATv2 per dst node (online softmax, bias, relu) ----------
// One wave per dst. Lane l: head h=l>>5, channels col=h*64+2*(l&31), col+1.
// The 3 relations' edge loops are INTERLEAVED (independent online-softmax
// state each) with a 1-deep gather prefetch per relation: ~3 loads in flight.
__global__ void gat3_k(GatA g, float* __restrict__ outF, unsigned short* __restrict__ outH,
                       int mode) {  // mode 0: relu -> bf16 outH ; mode 1: fp32 outF
    int w = (int)((blockIdx.x * blockDim.x + threadIdx.x) >> 6);
    int l = threadIdx.x & 63;
    if (w >= NN) return;
    int col = ((l >> 5) << 6) + ((l & 31) << 1);  // h*64 + 2*(l&31)

    const unsigned short* PL0 = g.PL[0];
    const unsigned short* PL1 = g.PL[1];
    const unsigned short* PL2 = g.PL[2];
    const int* cs0 = g.csrc[0];
    const int* cs1 = g.csrc[1];
    const int* cs2 = g.csrc[2];

    // per-relation dst-side values + att (log2e folded)
    unsigned grp0 = *(const unsigned*)(g.PR[0] + (long)w * 128 + col);
    unsigned grp1 = *(const unsigned*)(g.PR[1] + (long)w * 128 + col);
    unsigned grp2 = *(const unsigned*)(g.PR[2] + (long)w * 128 + col);
    float gr00 = __uint_as_float(grp0 << 16), gr01 = __uint_as_float(grp0 & 0xffff0000u);
    float gr10 = __uint_as_float(grp1 << 16), gr11 = __uint_as_float(grp1 & 0xffff0000u);
    float gr20 = __uint_as_float(grp2 << 16), gr21 = __uint_as_float(grp2 & 0xffff0000u);
    float at00 = g.att[0][col] * LOG2E, at01 = g.att[0][col + 1] * LOG2E;
    float at10 = g.att[1][col] * LOG2E, at11 = g.att[1][col + 1] * LOG2E;
    float at20 = g.att[2][col] * LOG2E, at21 = g.att[2][col + 1] * LOG2E;

    int i0 = g.rowp[0][w], e0 = g.rowp[0][w + 1];
    int i1 = g.rowp[1][w], e1 = g.rowp[1][w + 1];
    int i2 = g.rowp[2][w], e2 = g.rowp[2][w + 1];

    float m0 = -1e30f, sd0 = 0.f, A00 = 0.f, A01 = 0.f;
    float m1 = -1e30f, sd1 = 0.f, A10 = 0.f, A11 = 0.f;
    float m2 = -1e30f, sd2 = 0.f, A20 = 0.f, A21 = 0.f;

    bool h0 = i0 < e0, h1 = i1 < e1, h2 = i2 < e2;
    unsigned nx0 = 0, nx1 = 0, nx2 = 0;
    if (h0) {
        int s = __builtin_amdgcn_readfirstlane(cs0[i0]);
        nx0 = *(const unsigned*)(PL0 + (long)s * 128 + col);
    }
    if (h1) {
        int s = __builtin_amdgcn_readfirstlane(cs1[i1]);
        nx1 = *(const unsigned*)(PL1 + (long)s * 128 + col);
    }
    if (h2) {
        int s = __builtin_amdgcn_readfirstlane(cs2[i2]);
        nx2 = *(const unsigned*)(PL2 + (long)s * 128 + col);
    }

    // one online-softmax step; v reduced over 32 lanes (both heads at once)
#define GSTEP(gg, gr_0, gr_1, at_0, at_1, m_, sd_, A_0, A_1)                  \
    {                                                                         \
        float gl0 = __uint_as_float((gg) << 16);                              \
        float gl1 = __uint_as_float((gg) & 0xffff0000u);                      \
        float x0 = gl0 + (gr_0), x1 = gl1 + (gr_1);                           \
        float t0 = fmaxf(x0, 0.f) + 0.2f * fminf(x0, 0.f);                    \
        float t1 = fmaxf(x1, 0.f) + 0.2f * fminf(x1, 0.f);                    \
        float v = t0 * (at_0) + t1 * (at_1);                                  \
        v += __shfl_xor(v, 16);                                               \
        v += __shfl_xor(v, 8);                                                \
        v += __shfl_xor(v, 4);                                                \
        v += __shfl_xor(v, 2);                                                \
        v += __shfl_xor(v, 1);                                                \
        float mn = fmaxf(m_, v);                                              \
        float sc = __builtin_exp2f(m_ - mn);                                  \
        float p = __builtin_exp2f(v - mn);                                    \
        sd_ = sd_ * sc + p;                                                   \
        A_0 = A_0 * sc + p * gl0;                                             \
        A_1 = A_1 * sc + p * gl1;                                             \
        m_ = mn;                                                              \
    }

    while (h0 || h1 || h2) {
        if (h0) {
            unsigned gg = nx0;
            ++i0;
            h0 = i0 < e0;
            if (h0) {
                int s = __builtin_amdgcn_readfirstlane(cs0[i0]);
                nx0 = *(const unsigned*)(PL0 + (long)s * 128 + col);
            }
            GSTEP(gg, gr00, gr01, at00, at01, m0, sd0, A00, A01);
        }
        if (h1) {
            unsigned gg = nx1;
            ++i1;
            h1 = i1 < e1;
            if (h1) {
                int s = __builtin_amdgcn_readfirstlane(cs1[i1]);
                nx1 = *(const unsigned*)(PL1 + (long)s * 128 + col);
            }
            GSTEP(gg, gr10, gr11, at10, at11, m1, sd1, A10, A11);
        }
        if (h2) {
            unsigned gg = nx2;
            ++i2;
            h2 = i2 < e2;
            if (h2) {
                int s = __builtin_amdgcn_readfirstlane(cs2[i2]);
                nx2 = *(const unsigned*)(PL2 + (long)s * 128 + col);
            }
            GSTEP(gg, gr20, gr21, at20, at21, m2, sd2, A20, A21);
        }
    }
#undef GSTEP

    float acc0 = A00 / (sd0 + 1e-16f) + g.bias[0][col] + A10 / (sd1 + 1e-16f) +
                 g.bias[1][col] + A20 / (sd2 + 1e-16f) + g.bias[2][col];
    float acc1 = A01 / (sd0 + 1e-16f) + g.bias[0][col + 1] + A11 / (sd1 + 1e-16f) +
                 g.bias[1][col + 1] + A21 / (sd2 + 1e-16f) + g.bias[2][col + 1];

    long o = (long)w * 128 + col;
    if (mode == 0) {
        unsigned px = (unsigned)f2bf(fmaxf(acc0, 0.f)) |
                      ((unsigned)f2bf(fmaxf(acc1, 0.f)) << 16);
        *(unsigned*)(outH + o) = px;  // coalesced 256B/row
    } else {
        *(float2*)(outF + o) = make_float2(acc0, acc1);
    }
}

__global__ void sentinel_k(float* out) { out[0] = 123456.0f; }

extern "C" void kernel_launch(void* const* d_in, const int* in_sizes, int n_in,
                              void* d_out, int out_size, void* d_ws, size_t ws_size,
                              hipStream_t stream) {
    const float* xin[3] = {(const float*)d_in[0], (const float*)d_in[1], (const float*)d_in[2]};
    EPtrs ep;
    for (int r = 0; r < 9; ++r) ep.p[r] = (const int*)d_in[3 + r];
    const float* Win[3] = {(const float*)d_in[12], (const float*)d_in[14], (const float*)d_in[16]};
    const float* bin[3] = {(const float*)d_in[13], (const float*)d_in[15], (const float*)d_in[17]};
    const float* Wl[2] = {(const float*)d_in[18], (const float*)d_in[22]};
    const float* Wr[2] = {(const float*)d_in[19], (const float*)d_in[23]};
    const float* att[2] = {(const float*)d_in[20], (const float*)d_in[24]};
    const float* bc[2] = {(const float*)d_in[21], (const float*)d_in[25]};

    // ws: h1[3] h2[3] pl[3] pr[3] (bf16, NH each) | deg 9NN | bsum 9NB | rowp 9(NN+1) | csrc 9NE
    size_t nInt = (size_t)9 * NN + (size_t)9 * NB + (size_t)9 * (NN + 1) + (size_t)9 * NE;
    size_t need = (size_t)12 * NH * 2 + nInt * 4;
    if (ws_size < need) {
        hipMemsetAsync(d_out, 0, (size_t)out_size * 4, stream);
        sentinel_k<<<1, 1, 0, stream>>>((float*)d_out);
        return;
    }
    unsigned short* h1 = (unsigned short*)d_ws;
    unsigned short* h2 = h1 + (size_t)3 * NH;
    unsigned short* pl = h2 + (size_t)3 * NH;
    unsigned short* pr = pl + (size_t)3 * NH;
    int* deg = (int*)(pr + (size_t)3 * NH);
    int* bsum = deg + (size_t)9 * NN;
    int* rowp = bsum + (size_t)9 * NB;
    int* csrc = rowp + (size_t)9 * (NN + 1);

    static const int ST[9] = {0, 0, 1, 0, 2, 1, 2, 1, 2};
    static const int RT[3][3] = {{0, 2, 4}, {1, 6, 7}, {3, 5, 8}};  // relations per dst type

    for (int T = 0; T < 3; ++T)
        inproj_k<<<NN / 4, 256, 0, stream>>>(xin[T], Win[T], bin[T], h1 + (size_t)T * NH, NN);

    hipMemsetAsync(deg, 0, (size_t)9 * NN * 4, stream);
    dim3 eg((NE + 255) / 256, 9), ng(NB, 9);
    count_k<<<eg, 256, 0, stream>>>(ep, deg);
    scanA_k<<<ng, 256, 0, stream>>>(deg, bsum);
    scanB_k<<<9, 512, 0, stream>>>(bsum);
    scanC_k<<<ng, 256, 0, stream>>>(deg, bsum, rowp);
    scat_k<<<eg, 256, 0, stream>>>(ep, deg, csrc);

    dim3 gg((NN + 63) / 64, 6);
    for (int l = 0; l < 2; ++l) {
        unsigned short* hc = (l == 0) ? h1 : h2;
        for (int T = 0; T < 3; ++T) {
            G6 g6;
            GatA ga;
            for (int j = 0; j < 3; ++j) {
                int r = RT[T][j];
                g6.A[j] = hc + (size_t)ST[r] * NH;               // PL_j = h[src] @ Wl[r]
                g6.W[j] = Wl[l] + (size_t)r * 16384;
                g6.O[j] = pl + (size_t)j * NH;
                g6.A[3 + j] = hc + (size_t)T * NH;               // PR_j = h[T] @ Wr[r]
                g6.W[3 + j] = Wr[l] + (size_t)r * 16384;
                g6.O[3 + j] = pr + (size_t)j * NH;
                ga.PL[j] = pl + (size_t)j * NH;
                ga.PR[j] = pr + (size_t)j * NH;
                ga.rowp[j] = rowp + (size_t)r * (NN + 1);
                ga.csrc[j] = csrc + (size_t)r * NE;
                ga.att[j] = att[l] + (size_t)r * 128;
                ga.bias[j] = bc[l] + (size_t)r * 128;
            }
            gemm6_k<<<gg, 256, 0, stream>>>(g6, NN);
            if (l == 0)
                gat3_k<<<NN / 4, 256, 0, stream>>>(ga, nullptr, h2 + (size_t)T * NH, 0);
            else
                gat3_k<<<NN / 4, 256, 0, stream>>>(ga, (float*)d_out + (size_t)T * NH, nullptr, 1);
        }
    }
}